// Round 13
// baseline (258.267 us; speedup 1.0000x reference)
//
#include <hip/hip_runtime.h>
#include <math.h>

#define IMG_W 112
#define HW    12544          // 112*112
#define CI    8
#define CO    16
#define EPS   1e-6f

typedef __attribute__((ext_vector_type(8))) _Float16 half8;  // 4 VGPRs
typedef __attribute__((ext_vector_type(4))) float f32x4;

// Round 13: algebraic restructure. act[n,co] = sum_j xt_j * T[n,(j,co)] with
// T = Y * V0 a pure GEMM (K=72 patch positions in MFMA, not VALU folds);
// n2[n,co] = sum_{jj,kk} xt_jj xt_kk G[(jj,kk),co], G = V0^T V0 (Gram), a
// second small GEMM (K=81). Kernel1 (1 block) precomputes A-fragments and G
// into d_ws; kernel2 does 2 GEMMs + tiny epilogue per 64-pixel block.
// Fragment layouts (verified on-silicon r7-r12, 16x16x32):
//   A: lane l holds A[m=l&15][k=(l>>4)*8+j];  B: B[k=(l>>4)*8+j][n=l&15]
//   C/D: col=l&15, row=(l>>4)*4+reg.

// ---------------- kernel 1: prep (runs every call, 1 block) ----------------
__global__ __launch_bounds__(512) void coda_prep(
    const float* __restrict__ wp, const float* __restrict__ bp,
    _Float16* __restrict__ ws)
{
  __shared__ float sW[1152 * 8];   // 36864B
  __shared__ float sB[1152];       //  4608B
  __shared__ float sG[1536];       //  6144B fp32 G81 accum (192 units x 8)

  const int tid = threadIdx.x;
  for (int i = tid; i < 9216; i += 512) sW[i] = wp[i];
  for (int i = tid; i < 1152; i += 512) sB[i] = bp[i];
  for (int i = tid; i < 1536; i += 512) sG[i] = 0.f;
  __syncthreads();

  // A1 fragments: unit u = (kt*9+Mt)*64+l ; value V0[k*16+co, jj=Mt]
  for (int u = tid; u < 1728; u += 512) {
    const int kt = u / 576, rem = u - kt * 576;
    const int Mt = rem >> 6, l = rem & 63;
    const int co = l & 15, k0 = kt * 32 + ((l >> 4) << 3);
    half8 v;
#pragma unroll
    for (int j = 0; j < 8; ++j) {
      const int k = k0 + j;
      float f = 0.f;
      if (k < 72) {
        const int row = k * 16 + co;
        f = (Mt < 8) ? sW[row * 8 + Mt] : sB[row];
      }
      v[j] = (_Float16)f;
    }
    ((half8*)ws)[u] = v;
  }

  // G81 partials: task t = (unit u<192, p-chunk of 9); G[k=(jj,kk), co]
  for (int t = tid; t < 1536; t += 512) {
    const int u = t >> 3, chunk = t & 7;
    const int l = u & 63;
    const int co = l & 15, k0 = (u >> 6) * 32 + ((l >> 4) << 3);
    const int p0 = chunk * 9;
    float part[8];
#pragma unroll
    for (int j = 0; j < 8; ++j) part[j] = 0.f;
    for (int p = p0; p < p0 + 9; ++p) {
      const int row = p * 16 + co;
      float w0 = sW[row * 8 + 0], w1 = sW[row * 8 + 1];
      float w2 = sW[row * 8 + 2], w3 = sW[row * 8 + 3];
      float w4 = sW[row * 8 + 4], w5 = sW[row * 8 + 5];
      float w6 = sW[row * 8 + 6], w7 = sW[row * 8 + 7];
      float w8 = sB[row];
      auto sel = [&](int i) {
        float r = w0;
        r = (i == 1) ? w1 : r; r = (i == 2) ? w2 : r; r = (i == 3) ? w3 : r;
        r = (i == 4) ? w4 : r; r = (i == 5) ? w5 : r; r = (i == 6) ? w6 : r;
        r = (i == 7) ? w7 : r; r = (i == 8) ? w8 : r;
        return r;
      };
#pragma unroll
      for (int j = 0; j < 8; ++j) {
        const int k = k0 + j;
        if (k < 81) {
          const int jj = (k * 57) >> 9;     // k/9 for k<81
          const int kk = k - 9 * jj;
          part[j] += sel(jj) * sel(kk);
        }
      }
    }
#pragma unroll
    for (int j = 0; j < 8; ++j)
      if (k0 + j < 81) atomicAdd(&sG[u * 8 + j], part[j]);
  }
  __syncthreads();

  for (int u = tid; u < 192; u += 512) {
    half8 v;
#pragma unroll
    for (int j = 0; j < 8; ++j) v[j] = (_Float16)sG[u * 8 + j];
    ((half8*)ws)[1728 + u] = v;
  }
}

// ---------------- kernel 2: main (784 blocks x 512) ----------------
__global__ __launch_bounds__(512, 4) void coda_main(
    const float* __restrict__ in, const _Float16* __restrict__ ws,
    float* __restrict__ out)
{
  __shared__ half8 sA1[1728];      // 27648B GEMM1 A-frags
  __shared__ half8 sA2[192];       //  3072B GEMM2 A-frags (G81)
  __shared__ half8 sY[768];        // 12288B GEMM1 B-frags (patches)
  __shared__ float sIn[CI * 290];  //  9280B input halo (fp32)
  __shared__ float sAcc[1024];     //  4096B act accum [co*64+n]
  __shared__ float sN2[1024];      //  4096B n2 [co*64+n]   (total 60480B)

  const int tid = threadIdx.x;
  const int b   = blockIdx.x / 196;
  const int r0  = (blockIdx.x - b * 196) * 64;
  const float* __restrict__ inb = in + b * CI * HW;

  // stage fragments from ws (coalesced 16B)
  for (int i = tid; i < 1728; i += 512)
    ((float4*)sA1)[i] = ((const float4*)ws)[i];
  if (tid < 192) ((float4*)sA2)[tid] = ((const float4*)ws)[1728 + tid];
  // stage input halo [r0-113, r0+176] clamped
  for (int i = tid; i < CI * 290; i += 512) {
    const int c = i / 290, idx = i - c * 290;
    int g = r0 - 113 + idx;
    g = (g < 0) ? 0 : (g > HW - 1 ? HW - 1 : g);
    sIn[i] = inb[c * HW + g];
  }
  for (int i = tid; i < 1024; i += 512) sAcc[i] = 0.f;
  __syncthreads();

  // build Y B-frags: unit u = kt*256 + Nt*64 + l
  for (int u = tid; u < 768; u += 512) {
    const int kt = u >> 8, rem = u & 255;
    const int Nt = rem >> 6, l = rem & 63;
    const int n = Nt * 16 + (l & 15);
    const int pos = r0 + n;
    const int h = pos / IMG_W, w = pos - h * IMG_W;
    const int off = 113 + n;
    const int k0 = kt * 32 + ((l >> 4) << 3);
    half8 v;
#pragma unroll
    for (int j = 0; j < 8; ++j) {
      const int k = k0 + j;
      float y = 0.f;
      if (k < 72) {
        const int c = (k * 57) >> 9;        // k/9
        const int q = k - 9 * c;
        const int kh = (q * 11) >> 5;       // q/3
        const int kw = q - 3 * kh;
        const bool ok = ((unsigned)(h + kh - 1) < 112u) &&
                        ((unsigned)(w + kw - 1) < 112u);
        y = ok ? sIn[c * 290 + off + kh * IMG_W + kw - 113] : 0.f;
      }
      v[j] = (_Float16)y;
    }
    sY[u] = v;
  }
  __syncthreads();

  // 40 tile-units, 5 per wave: u<36 -> GEMM1 (Mt=u>>2, Nt=u&3);
  // u>=36 -> GEMM2 for Nt=u-36.
  const int wave = tid >> 6, l = tid & 63;
#pragma unroll
  for (int s = 0; s < 5; ++s) {
    const int u = wave * 5 + s;
    if (u < 36) {
      const int Mt = u >> 2, Nt = u & 3;
      f32x4 d = {0.f, 0.f, 0.f, 0.f};
#pragma unroll
      for (int kt = 0; kt < 3; ++kt)
        d = __builtin_amdgcn_mfma_f32_16x16x32_f16(
            sA1[(kt * 9 + Mt) * 64 + l], sY[(kt * 4 + Nt) * 64 + l], d, 0, 0, 0);
      const int n = Nt * 16 + (l & 15);
      const float xj = (Mt < 8) ? sIn[Mt * 290 + 113 + n] : 1.0f;
#pragma unroll
      for (int i = 0; i < 4; ++i)
        atomicAdd(&sAcc[(((l >> 4) << 2) + i) * 64 + n], xj * d[i]);
    } else {
      const int Nt = u - 36;
      const int n = Nt * 16 + (l & 15);
      float x0 = sIn[0 * 290 + 113 + n], x1 = sIn[1 * 290 + 113 + n];
      float x2 = sIn[2 * 290 + 113 + n], x3 = sIn[3 * 290 + 113 + n];
      float x4 = sIn[4 * 290 + 113 + n], x5 = sIn[5 * 290 + 113 + n];
      float x6 = sIn[6 * 290 + 113 + n], x7 = sIn[7 * 290 + 113 + n];
      auto sel = [&](int i) {
        float r = x0;
        r = (i == 1) ? x1 : r; r = (i == 2) ? x2 : r; r = (i == 3) ? x3 : r;
        r = (i == 4) ? x4 : r; r = (i == 5) ? x5 : r; r = (i == 6) ? x6 : r;
        r = (i == 7) ? x7 : r; r = (i == 8) ? 1.0f : r;
        return r;
      };
      f32x4 d = {0.f, 0.f, 0.f, 0.f};
      const int kq = (l >> 4) << 3;
#pragma unroll
      for (int kt = 0; kt < 3; ++kt) {
        half8 z;
#pragma unroll
        for (int j = 0; j < 8; ++j) {
          const int k = kt * 32 + kq + j;
          const int jj = (k * 57) >> 9;
          float zv = 0.f;
          if (jj < 9) zv = sel(jj) * sel(k - 9 * jj);
          z[j] = (_Float16)zv;
        }
        d = __builtin_amdgcn_mfma_f32_16x16x32_f16(sA2[kt * 64 + l], z, d, 0, 0, 0);
      }
#pragma unroll
      for (int i = 0; i < 4; ++i)
        sN2[(((l >> 4) << 2) + i) * 64 + n] = d[i];
    }
  }
  __syncthreads();

  // final: 2 outputs per thread, n-coalesced
  for (int u = tid; u < 1024; u += 512) {
    const int co = u >> 6, n = u & 63;
    out[(long)b * CO * HW + (long)co * HW + r0 + n] =
        sAcc[u] / (sqrtf(sN2[u]) + EPS);
  }
}

extern "C" void kernel_launch(void* const* d_in, const int* in_sizes, int n_in,
                              void* d_out, int out_size, void* d_ws, size_t ws_size,
                              hipStream_t stream) {
  const float* in = (const float*)d_in[0];
  const float* wp = (const float*)d_in[1];
  const float* bp = (const float*)d_in[2];
  float* out = (float*)d_out;
  _Float16* ws = (_Float16*)d_ws;   // needs 30720 B

  coda_prep<<<dim3(1),   dim3(512), 0, stream>>>(wp, bp, ws);
  coda_main<<<dim3(784), dim3(512), 0, stream>>>(in, ws, out);
}